// Round 6
// baseline (443.262 us; speedup 1.0000x reference)
//
#include <hip/hip_runtime.h>
#include <hip/hip_bf16.h>

#define DIM 96
typedef unsigned int u32;
typedef unsigned long long u64;
typedef __attribute__((ext_vector_type(8))) short short8;
typedef __attribute__((ext_vector_type(4))) float f32x4;

__device__ __forceinline__ u32 bfr(float f) {           // f32 -> bf16 bits (RNE)
    u32 b = __float_as_uint(f);
    return (b + 0x7fffu + ((b >> 16) & 1u)) >> 16;
}
__device__ __forceinline__ u32 pk2(float lo, float hi) { return bfr(lo) | (bfr(hi) << 16); }
__device__ __forceinline__ float bl(u32 u) { return __uint_as_float(u << 16); }
__device__ __forceinline__ float bh(u32 u) { return __uint_as_float(u & 0xffff0000u); }

// ---------------- packed degree+count (64B-padded) + rank; bounds tail ----------------
// zone[node*8] = (count << 32) | sum(w * 2^24); one u64 atomic per edge.
__global__ void k_deg(const int* __restrict__ ei, const int* __restrict__ ein,
                      const float* __restrict__ ew, const float* __restrict__ ewn,
                      u64* __restrict__ zone, u32* __restrict__ rank_o, u32* __restrict__ rank_n,
                      const int* __restrict__ batch, int* __restrict__ gs, int* __restrict__ ge,
                      int E, int n) {
    int e = blockIdx.x * 256 + threadIdx.x;
    if (blockIdx.y == 0 && e < n) {
        int b = batch[e];
        if (e == 0 || batch[e - 1] != b) atomicMin(&gs[b], e);
        if (e == n - 1 || batch[e + 1] != b) atomicMax(&ge[b], e + 1);
    }
    if (e >= E) return;
    const int*   I = blockIdx.y ? ein : ei;
    const float* W = blockIdx.y ? ewn : ew;
    u64* z = zone + (blockIdx.y ? (size_t)n * 8 : 0);
    u32* rk = blockIdx.y ? rank_n : rank_o;
    int d = I[E + e];
    u32 wfix = (u32)(W[e] * 16777216.0f + 0.5f);
    u64 old = atomicAdd(&z[(size_t)d * 8], ((u64)1 << 32) | (u64)wfix);
    rk[e] = (u32)(old >> 32);
}

// ---------------- zone -> dinv over 2N ----------------
__global__ void k_dinv(const u64* __restrict__ zone, float* __restrict__ dinv, int n2) {
    int i = blockIdx.x * 256 + threadIdx.x;
    if (i >= n2) return;
    u64 p = zone[(size_t)i * 8];
    float s = (float)(u32)p * 5.9604644775390625e-8f;   // 2^-24
    dinv[i] = rsqrtf(s + 1.0f);
}

// ---------------- exclusive scan of counts (zone hi words), st[n] = total ----------------
__global__ __launch_bounds__(1024) void k_scan(
    const u64* __restrict__ zone, int* __restrict__ st0, int* __restrict__ st1, int n)
{
    const u64* c = zone + (blockIdx.x ? (size_t)n * 8 : 0);
    int* st = blockIdx.x ? st1 : st0;
    __shared__ int wsum[16];
    __shared__ int carry_s;
    int tid = threadIdx.x, lane = tid & 63, wid = tid >> 6;
    if (tid == 0) carry_s = 0;
    __syncthreads();
    for (int base = 0; base < n; base += 16384) {
        int i0 = base + tid * 16;
        int v[16];
        #pragma unroll
        for (int k = 0; k < 16; ++k)
            v[k] = (i0 + k < n) ? (int)(c[(size_t)(i0 + k) * 8] >> 32) : 0;
        int ex[16]; int run = 0;
        #pragma unroll
        for (int k = 0; k < 16; ++k) { ex[k] = run; run += v[k]; }
        int tsum = run, winc = tsum;
        #pragma unroll
        for (int d = 1; d < 64; d <<= 1) {
            int t = __shfl_up(winc, d);
            if (lane >= d) winc += t;
        }
        if (lane == 63) wsum[wid] = winc;
        __syncthreads();
        if (wid == 0) {
            int y = (lane < 16) ? wsum[lane] : 0;
            #pragma unroll
            for (int d = 1; d < 16; d <<= 1) {
                int t = __shfl_up(y, d);
                if (lane >= d) y += t;
            }
            if (lane < 16) wsum[lane] = y;
        }
        __syncthreads();
        int woff = (wid > 0) ? wsum[wid - 1] : 0;
        int tbase = carry_s + woff + winc - tsum;
        if (i0 < n) {
            #pragma unroll
            for (int k = 0; k < 16; ++k) if (i0 + k < n) st[i0 + k] = tbase + ex[k];
        }
        __syncthreads();
        if (tid == 0) carry_s += wsum[15];
        __syncthreads();
    }
    if (tid == 0) st[n] = carry_s;
}

// ---------------- atomic-free scatter: ev[st[dst]+rank] = [w_f32 | src] ----------------
__global__ void k_scatter(const int* __restrict__ ei, const float* __restrict__ ew,
                          const int* __restrict__ ein, const float* __restrict__ ewn,
                          const u32* __restrict__ rank_o, const u32* __restrict__ rank_n,
                          const int* __restrict__ st_o, const int* __restrict__ st_n,
                          u64* __restrict__ ev_o, u64* __restrict__ ev_n, int E) {
    int e = blockIdx.x * 256 + threadIdx.x;
    if (e >= E) return;
    const int*   I = blockIdx.y ? ein : ei;
    const float* W = blockIdx.y ? ewn : ew;
    const u32*   R = blockIdx.y ? rank_n : rank_o;
    const int*   st = blockIdx.y ? st_n : st_o;
    u64* ev = blockIdx.y ? ev_n : ev_o;
    int s = I[e], d = I[E + e];
    int slot = st[d] + (int)R[e];
    ev[slot] = ((u64)__float_as_uint(W[e]) << 32) | (u32)s;
}

// ---------------- combined weights -> bf16 K-major Wt[96][192]; bias f32; rinv ----------------
__global__ void k_combine(
    const float* __restrict__ W0o, const float* __restrict__ W0n, const float* __restrict__ W0f,
    const float* __restrict__ b0o, const float* __restrict__ b0n, const float* __restrict__ b0f,
    const float* __restrict__ W1o, const float* __restrict__ W1n, const float* __restrict__ W1f,
    const float* __restrict__ b1o, const float* __restrict__ b1n, const float* __restrict__ b1f,
    unsigned short* __restrict__ Wt, float* __restrict__ bc,
    const int* __restrict__ gs, const int* __restrict__ ge, float* __restrict__ rinv)
{
    if (blockIdx.y == 0 && blockIdx.x == 0 && threadIdx.x < 64) {
        int c = ge[threadIdx.x] - gs[threadIdx.x];
        if (c < 1) c = 1;
        rinv[threadIdx.x] = 1.0f / (float)c;
    }
    int l = blockIdx.y;
    const float* Wo = l ? W1o : W0o;
    const float* Wn = l ? W1n : W0n;
    const float* Wf = l ? W1f : W0f;
    const float* bo = l ? b1o : b0o;
    const float* bn = l ? b1n : b0n;
    const float* bf = l ? b1f : b0f;
    unsigned short* wt = Wt + (size_t)l * 96 * 192;
    float* bcl = bc + l * DIM;
    int g = blockIdx.x * 256 + threadIdx.x;
    if (g >= DIM * DIM) return;
    int i = g / DIM, j = g % DIM;       // i = k-row, j = out col
    float so = 0.f, sn = 0.f;
    for (int k = 0; k < DIM; ++k) {
        so += Wo[i * DIM + k] * Wf[k * DIM + j];
        sn += Wn[i * DIM + k] * Wf[(DIM + k) * DIM + j];
    }
    wt[j * 192 + i]      = (unsigned short)bfr(so);
    wt[j * 192 + 96 + i] = (unsigned short)bfr(sn);
    if (i == 0) {
        float s = bf[j];
        for (int k = 0; k < DIM; ++k)
            s += bo[k] * Wf[k * DIM + j] + bn[k] * Wf[(DIM + k) * DIM + j];
        bcl[j] = s;
    }
}

// ---------------- cast x (f32) -> packed bf16 ----------------
__global__ void k_cast(const float* __restrict__ x, u32* __restrict__ Xh, int total8) {
    int i = blockIdx.x * 256 + threadIdx.x;
    if (i >= total8) return;
    const float4* xv = (const float4*)x;
    float4 a = xv[i * 2], b = xv[i * 2 + 1];
    uint4 o;
    o.x = pk2(a.x, a.y); o.y = pk2(a.z, a.w);
    o.z = pk2(b.x, b.y); o.w = pk2(b.z, b.w);
    ((uint4*)Xh)[i] = o;
}

// ---------------- aggregation: 16 edge-groups x 4 lanes; lane owns 24 cols ----------------
__global__ __launch_bounds__(256) void k_agg(
    const u32* __restrict__ Xh,
    const int* __restrict__ st_o, const u64* __restrict__ ev_o,
    const int* __restrict__ st_n, const u64* __restrict__ ev_n,
    const float* __restrict__ dinv,
    u32* __restrict__ fAB, int n)
{
    int wid = (blockIdx.x * 256 + threadIdx.x) >> 6;
    if (wid >= n) return;
    int lane = threadIdx.x & 63;
    int sl = lane & 3;          // col chunk: u32s [sl*12, sl*12+12) of the 48-u32 row
    int g  = lane >> 2;         // 16 edge groups
    const int* st; const u64* ev; const float* dv; int co;
    if (blockIdx.y) { st = st_n; ev = ev_n; dv = dinv + n; co = 48; }
    else            { st = st_o; ev = ev_o; dv = dinv;     co = 0; }

    float dr = dv[wid];
    float acc[24];
    #pragma unroll
    for (int k = 0; k < 24; ++k) acc[k] = 0.f;

    const u32* xrow;
    int s = st[wid], e = st[wid + 1];
    for (int j = s + g; j < e; j += 16) {
        u64 ee = ev[j];
        int u = (int)(u32)ee;
        float w = __uint_as_float((u32)(ee >> 32)) * dr * dv[u];
        xrow = Xh + (size_t)u * 48 + sl * 12;
        uint4 q0 = *(const uint4*)(xrow);
        uint4 q1 = *(const uint4*)(xrow + 4);
        uint4 q2 = *(const uint4*)(xrow + 8);
        acc[0]  += w * bl(q0.x); acc[1]  += w * bh(q0.x);
        acc[2]  += w * bl(q0.y); acc[3]  += w * bh(q0.y);
        acc[4]  += w * bl(q0.z); acc[5]  += w * bh(q0.z);
        acc[6]  += w * bl(q0.w); acc[7]  += w * bh(q0.w);
        acc[8]  += w * bl(q1.x); acc[9]  += w * bh(q1.x);
        acc[10] += w * bl(q1.y); acc[11] += w * bh(q1.y);
        acc[12] += w * bl(q1.z); acc[13] += w * bh(q1.z);
        acc[14] += w * bl(q1.w); acc[15] += w * bh(q1.w);
        acc[16] += w * bl(q2.x); acc[17] += w * bh(q2.x);
        acc[18] += w * bl(q2.y); acc[19] += w * bh(q2.y);
        acc[20] += w * bl(q2.z); acc[21] += w * bh(q2.z);
        acc[22] += w * bl(q2.w); acc[23] += w * bh(q2.w);
    }
    if (g == 0) {               // self-loop term
        float d2 = dr * dr;
        xrow = Xh + (size_t)wid * 48 + sl * 12;
        uint4 q0 = *(const uint4*)(xrow);
        uint4 q1 = *(const uint4*)(xrow + 4);
        uint4 q2 = *(const uint4*)(xrow + 8);
        acc[0]  += d2 * bl(q0.x); acc[1]  += d2 * bh(q0.x);
        acc[2]  += d2 * bl(q0.y); acc[3]  += d2 * bh(q0.y);
        acc[4]  += d2 * bl(q0.z); acc[5]  += d2 * bh(q0.z);
        acc[6]  += d2 * bl(q0.w); acc[7]  += d2 * bh(q0.w);
        acc[8]  += d2 * bl(q1.x); acc[9]  += d2 * bh(q1.x);
        acc[10] += d2 * bl(q1.y); acc[11] += d2 * bh(q1.y);
        acc[12] += d2 * bl(q1.z); acc[13] += d2 * bh(q1.z);
        acc[14] += d2 * bl(q1.w); acc[15] += d2 * bh(q1.w);
        acc[16] += d2 * bl(q2.x); acc[17] += d2 * bh(q2.x);
        acc[18] += d2 * bl(q2.y); acc[19] += d2 * bh(q2.y);
        acc[20] += d2 * bl(q2.z); acc[21] += d2 * bh(q2.z);
        acc[22] += d2 * bl(q2.w); acc[23] += d2 * bh(q2.w);
    }
    #pragma unroll
    for (int d = 4; d < 64; d <<= 1) {
        #pragma unroll
        for (int k = 0; k < 24; ++k) acc[k] += __shfl_xor(acc[k], d);
    }
    if (g == 0) {
        u32* O = fAB + (size_t)wid * 96 + co + sl * 12;
        uint4 o0, o1, o2;
        o0.x = pk2(acc[0],  acc[1]);  o0.y = pk2(acc[2],  acc[3]);
        o0.z = pk2(acc[4],  acc[5]);  o0.w = pk2(acc[6],  acc[7]);
        o1.x = pk2(acc[8],  acc[9]);  o1.y = pk2(acc[10], acc[11]);
        o1.z = pk2(acc[12], acc[13]); o1.w = pk2(acc[14], acc[15]);
        o2.x = pk2(acc[16], acc[17]); o2.y = pk2(acc[18], acc[19]);
        o2.z = pk2(acc[20], acc[21]); o2.w = pk2(acc[22], acc[23]);
        *(uint4*)(O)     = o0;
        *(uint4*)(O + 4) = o1;
        *(uint4*)(O + 8) = o2;
    }
}

// ---------------- MFMA GEMM: relu(fAB[N][192]bf16 @ Wt + bias); pool; bf16 H ----------------
__global__ __launch_bounds__(256) void k_mmp(
    const u32* __restrict__ fAB, const unsigned short* __restrict__ Wtg,
    const float* __restrict__ bias, const int* __restrict__ batch,
    const int* __restrict__ gs, const int* __restrict__ ge,
    const float* __restrict__ rinv, float* __restrict__ outp,
    u32* __restrict__ Hh, int writeH, int n)
{
    __shared__ unsigned short sW[96 * 200];       // Wt: [col][k], padded stride 200
    __shared__ float tile[64][100];
    int tid = threadIdx.x;
    for (int m = tid; m < 2304; m += 256) {       // 96*192/8 short8 chunks
        int j = m / 24, k = (m % 24) * 8;
        *(uint4*)&sW[j * 200 + k] = *(const uint4*)&Wtg[j * 192 + k];
    }
    __syncthreads();
    int r0 = blockIdx.x * 64;
    int rows = min(64, n - r0);
    int lane = tid & 63, wv = tid >> 6;
    int rl = lane & 15;
    int kg = lane >> 4;
    int rowg = r0 + wv * 16 + rl;
    int rc = min(rowg, n - 1);
    const short8* Arow = (const short8*)(fAB + (size_t)rc * 96);
    f32x4 acc[6];
    #pragma unroll
    for (int c = 0; c < 6; ++c) acc[c] = (f32x4){0.f, 0.f, 0.f, 0.f};
    #pragma unroll
    for (int t = 0; t < 6; ++t) {
        short8 a = Arow[t * 4 + kg];
        #pragma unroll
        for (int c = 0; c < 6; ++c) {
            short8 b = *(const short8*)&sW[(c * 16 + rl) * 200 + t * 32 + kg * 8];
            acc[c] = __builtin_amdgcn_mfma_f32_16x16x32_bf16(a, b, acc[c], 0, 0, 0);
        }
    }
    #pragma unroll
    for (int c = 0; c < 6; ++c) {
        int col = c * 16 + rl;
        float bs = bias[col];
        #pragma unroll
        for (int q = 0; q < 4; ++q) {
            int lr = wv * 16 + kg * 4 + q;
            tile[lr][col] = fmaxf(acc[c][q] + bs, 0.f);
        }
    }
    __syncthreads();
    if (writeH) {
        for (int m = tid; m < rows * 48; m += 256) {
            int row = m / 48, cp = m % 48;
            Hh[(size_t)(r0 + row) * 48 + cp] = pk2(tile[row][cp * 2], tile[row][cp * 2 + 1]);
        }
    }
    if (tid < DIM) {
        int gfirst = batch[r0], glast = batch[r0 + rows - 1];
        for (int g = gfirst; g <= glast; ++g) {
            int lo = max(gs[g] - r0, 0), hi = min(ge[g] - r0, rows);
            if (lo < hi) {
                float s = 0.f;
                for (int r = lo; r < hi; ++r) s += tile[r][tid];
                atomicAdd(&outp[g * DIM + tid], s * rinv[g]);
            }
        }
    }
}

extern "C" void kernel_launch(void* const* d_in, const int* in_sizes, int n_in,
                              void* d_out, int out_size, void* d_ws, size_t ws_size,
                              hipStream_t stream)
{
    const float* x     = (const float*)d_in[0];
    const int*   ei    = (const int*)d_in[1];
    const float* ew    = (const float*)d_in[2];
    const int*   batch = (const int*)d_in[3];
    const int*   ein   = (const int*)d_in[4];
    const float* ewn   = (const float*)d_in[5];
    const float* W0o = (const float*)d_in[7];
    const float* b0o = (const float*)d_in[8];
    const float* W0n = (const float*)d_in[9];
    const float* b0n = (const float*)d_in[10];
    const float* W0f = (const float*)d_in[11];
    const float* b0f = (const float*)d_in[12];
    const float* W1o = (const float*)d_in[13];
    const float* b1o = (const float*)d_in[14];
    const float* W1n = (const float*)d_in[15];
    const float* b1n = (const float*)d_in[16];
    const float* W1f = (const float*)d_in[17];
    const float* b1f = (const float*)d_in[18];

    const int N = in_sizes[0] / DIM;
    const int E = in_sizes[2];
    float* out = (float*)d_out;

    char* ws = (char*)d_ws;
    size_t off = 0;
    auto alloc = [&](size_t bytes) -> char* {
        char* p = ws + off;
        off += (bytes + 255) & ~(size_t)255;
        return p;
    };
    u64*   zone   = (u64*)alloc((size_t)2 * N * 8 * 8);   // 64B-padded packed counters
    u32*   rank_o = (u32*)alloc((size_t)E * 4);
    u32*   rank_n = (u32*)alloc((size_t)E * 4);
    int*   st_o   = (int*)alloc((size_t)(N + 1) * 4);
    int*   st_n   = (int*)alloc((size_t)(N + 1) * 4);
    u64*   ev_o   = (u64*)alloc((size_t)E * 8);
    u64*   ev_n   = (u64*)alloc((size_t)E * 8);
    float* dinv   = (float*)alloc((size_t)2 * N * 4);
    u32*   Xh     = (u32*)alloc((size_t)N * 48 * 4);
    u32*   Hh     = (u32*)alloc((size_t)N * 48 * 4);
    u32*   fAB    = (u32*)alloc((size_t)N * 96 * 4);
    unsigned short* Wt = (unsigned short*)alloc((size_t)2 * 96 * 192 * 2);
    float* bc     = (float*)alloc(2 * DIM * 4);
    float* rinv   = (float*)alloc(64 * 4);
    int*   gs     = (int*)alloc(64 * 4);
    int*   ge     = (int*)alloc(64 * 4);

    int eb = (E + 255) / 256;

    hipMemsetAsync(zone, 0, (size_t)2 * N * 8 * 8, stream);
    hipMemsetAsync(gs, 0x7f, 64 * 4, stream);
    hipMemsetAsync(ge, 0, 64 * 4, stream);
    hipMemsetAsync(out, 0, (size_t)out_size * 4, stream);

    k_deg<<<dim3(eb, 2), 256, 0, stream>>>(ei, ein, ew, ewn, zone, rank_o, rank_n,
                                           batch, gs, ge, E, N);
    k_dinv<<<(2 * N + 255) / 256, 256, 0, stream>>>(zone, dinv, 2 * N);
    k_scan<<<2, 1024, 0, stream>>>(zone, st_o, st_n, N);
    k_scatter<<<dim3(eb, 2), 256, 0, stream>>>(ei, ew, ein, ewn, rank_o, rank_n,
                                               st_o, st_n, ev_o, ev_n, E);
    k_combine<<<dim3(36, 2), 256, 0, stream>>>(W0o, W0n, W0f, b0o, b0n, b0f,
                                               W1o, W1n, W1f, b1o, b1n, b1f,
                                               Wt, bc, gs, ge, rinv);
    k_cast<<<(N * 12 + 255) / 256, 256, 0, stream>>>(x, Xh, N * 12);

    dim3 ag(((size_t)N * 64 + 255) / 256, 2);
    int mb = (N + 63) / 64;

    // layer 0
    k_agg<<<ag, 256, 0, stream>>>(Xh, st_o, ev_o, st_n, ev_n, dinv, fAB, N);
    k_mmp<<<mb, 256, 0, stream>>>(fAB, Wt, bc, batch, gs, ge, rinv, out, Hh, 1, N);
    // layer 1
    k_agg<<<ag, 256, 0, stream>>>(Hh, st_o, ev_o, st_n, ev_n, dinv, fAB, N);
    k_mmp<<<mb, 256, 0, stream>>>(fAB, Wt + (size_t)96 * 192, bc + DIM, batch, gs, ge, rinv,
                                  out + 64 * DIM, Hh, 0, N);
}

// Round 7
// 354.533 us; speedup vs baseline: 1.2503x; 1.2503x over previous
//
#include <hip/hip_runtime.h>
#include <hip/hip_bf16.h>

#define DIM 96
typedef unsigned int u32;
typedef unsigned long long u64;
typedef __attribute__((ext_vector_type(8))) short short8;
typedef __attribute__((ext_vector_type(4))) float f32x4;

__device__ __forceinline__ u32 bfr(float f) {           // f32 -> bf16 bits (RNE)
    u32 b = __float_as_uint(f);
    return (b + 0x7fffu + ((b >> 16) & 1u)) >> 16;
}
__device__ __forceinline__ u32 pk2(float lo, float hi) { return bfr(lo) | (bfr(hi) << 16); }
__device__ __forceinline__ float bl(u32 u) { return __uint_as_float(u << 16); }
__device__ __forceinline__ float bh(u32 u) { return __uint_as_float(u & 0xffff0000u); }

struct __align__(4) U3 { u32 a, b, c; };

// ---------------- packed degree+count (64B-padded) + rank; bounds tail ----------------
// zone[node*8] = (count << 32) | sum(w * 2^24); one u64 atomic per edge.
__global__ void k_deg(const int* __restrict__ ei, const int* __restrict__ ein,
                      const float* __restrict__ ew, const float* __restrict__ ewn,
                      u64* __restrict__ zone, u32* __restrict__ rank_o, u32* __restrict__ rank_n,
                      const int* __restrict__ batch, int* __restrict__ gs, int* __restrict__ ge,
                      int E, int n) {
    int e = blockIdx.x * 256 + threadIdx.x;
    if (blockIdx.y == 0 && e < n) {
        int b = batch[e];
        if (e == 0 || batch[e - 1] != b) atomicMin(&gs[b], e);
        if (e == n - 1 || batch[e + 1] != b) atomicMax(&ge[b], e + 1);
    }
    if (e >= E) return;
    const int*   I = blockIdx.y ? ein : ei;
    const float* W = blockIdx.y ? ewn : ew;
    u64* z = zone + (blockIdx.y ? (size_t)n * 8 : 0);
    u32* rk = blockIdx.y ? rank_n : rank_o;
    int d = I[E + e];
    u32 wfix = (u32)(W[e] * 16777216.0f + 0.5f);
    u64 old = atomicAdd(&z[(size_t)d * 8], ((u64)1 << 32) | (u64)wfix);
    rk[e] = (u32)(old >> 32);
}

// ---------------- zone -> dinv over 2N ----------------
__global__ void k_dinv(const u64* __restrict__ zone, float* __restrict__ dinv, int n2) {
    int i = blockIdx.x * 256 + threadIdx.x;
    if (i >= n2) return;
    u64 p = zone[(size_t)i * 8];
    float s = (float)(u32)p * 5.9604644775390625e-8f;   // 2^-24
    dinv[i] = rsqrtf(s + 1.0f);
}

// ---------------- exclusive scan of counts (zone hi words), st[n] = total ----------------
__global__ __launch_bounds__(1024) void k_scan(
    const u64* __restrict__ zone, int* __restrict__ st0, int* __restrict__ st1, int n)
{
    const u64* c = zone + (blockIdx.x ? (size_t)n * 8 : 0);
    int* st = blockIdx.x ? st1 : st0;
    __shared__ int wsum[16];
    __shared__ int carry_s;
    int tid = threadIdx.x, lane = tid & 63, wid = tid >> 6;
    if (tid == 0) carry_s = 0;
    __syncthreads();
    for (int base = 0; base < n; base += 16384) {
        int i0 = base + tid * 16;
        int v[16];
        #pragma unroll
        for (int k = 0; k < 16; ++k)
            v[k] = (i0 + k < n) ? (int)(c[(size_t)(i0 + k) * 8] >> 32) : 0;
        int ex[16]; int run = 0;
        #pragma unroll
        for (int k = 0; k < 16; ++k) { ex[k] = run; run += v[k]; }
        int tsum = run, winc = tsum;
        #pragma unroll
        for (int d = 1; d < 64; d <<= 1) {
            int t = __shfl_up(winc, d);
            if (lane >= d) winc += t;
        }
        if (lane == 63) wsum[wid] = winc;
        __syncthreads();
        if (wid == 0) {
            int y = (lane < 16) ? wsum[lane] : 0;
            #pragma unroll
            for (int d = 1; d < 16; d <<= 1) {
                int t = __shfl_up(y, d);
                if (lane >= d) y += t;
            }
            if (lane < 16) wsum[lane] = y;
        }
        __syncthreads();
        int woff = (wid > 0) ? wsum[wid - 1] : 0;
        int tbase = carry_s + woff + winc - tsum;
        if (i0 < n) {
            #pragma unroll
            for (int k = 0; k < 16; ++k) if (i0 + k < n) st[i0 + k] = tbase + ex[k];
        }
        __syncthreads();
        if (tid == 0) carry_s += wsum[15];
        __syncthreads();
    }
    if (tid == 0) st[n] = carry_s;
}

// ------- atomic-free scatter: ev[st[dst]+rank] = [norm_f32 | src], norm fully folded -------
__global__ void k_scatter(const int* __restrict__ ei, const float* __restrict__ ew,
                          const int* __restrict__ ein, const float* __restrict__ ewn,
                          const u32* __restrict__ rank_o, const u32* __restrict__ rank_n,
                          const int* __restrict__ st_o, const int* __restrict__ st_n,
                          const float* __restrict__ dinv,
                          u64* __restrict__ ev_o, u64* __restrict__ ev_n, int E, int n) {
    int e = blockIdx.x * 256 + threadIdx.x;
    if (e >= E) return;
    const int*   I = blockIdx.y ? ein : ei;
    const float* W = blockIdx.y ? ewn : ew;
    const u32*   R = blockIdx.y ? rank_n : rank_o;
    const int*   st = blockIdx.y ? st_n : st_o;
    const float* dv = dinv + (blockIdx.y ? n : 0);
    u64* ev = blockIdx.y ? ev_n : ev_o;
    int s = I[e], d = I[E + e];
    float nrm = dv[s] * W[e] * dv[d];
    int slot = st[d] + (int)R[e];
    ev[slot] = ((u64)__float_as_uint(nrm) << 32) | (u32)s;
}

// ---------------- combined weights -> bf16 K-major Wt[96][192]; bias f32; rinv ----------------
__global__ void k_combine(
    const float* __restrict__ W0o, const float* __restrict__ W0n, const float* __restrict__ W0f,
    const float* __restrict__ b0o, const float* __restrict__ b0n, const float* __restrict__ b0f,
    const float* __restrict__ W1o, const float* __restrict__ W1n, const float* __restrict__ W1f,
    const float* __restrict__ b1o, const float* __restrict__ b1n, const float* __restrict__ b1f,
    unsigned short* __restrict__ Wt, float* __restrict__ bc,
    const int* __restrict__ gs, const int* __restrict__ ge, float* __restrict__ rinv)
{
    if (blockIdx.y == 0 && blockIdx.x == 0 && threadIdx.x < 64) {
        int c = ge[threadIdx.x] - gs[threadIdx.x];
        if (c < 1) c = 1;
        rinv[threadIdx.x] = 1.0f / (float)c;
    }
    int l = blockIdx.y;
    const float* Wo = l ? W1o : W0o;
    const float* Wn = l ? W1n : W0n;
    const float* Wf = l ? W1f : W0f;
    const float* bo = l ? b1o : b0o;
    const float* bn = l ? b1n : b0n;
    const float* bf = l ? b1f : b0f;
    unsigned short* wt = Wt + (size_t)l * 96 * 192;
    float* bcl = bc + l * DIM;
    int g = blockIdx.x * 256 + threadIdx.x;
    if (g >= DIM * DIM) return;
    int i = g / DIM, j = g % DIM;       // i = k-row, j = out col
    float so = 0.f, sn = 0.f;
    for (int k = 0; k < DIM; ++k) {
        so += Wo[i * DIM + k] * Wf[k * DIM + j];
        sn += Wn[i * DIM + k] * Wf[(DIM + k) * DIM + j];
    }
    wt[j * 192 + i]      = (unsigned short)bfr(so);
    wt[j * 192 + 96 + i] = (unsigned short)bfr(sn);
    if (i == 0) {
        float s = bf[j];
        for (int k = 0; k < DIM; ++k)
            s += bo[k] * Wf[k * DIM + j] + bn[k] * Wf[(DIM + k) * DIM + j];
        bcl[j] = s;
    }
}

// ---------------- cast x (f32) -> packed bf16 ----------------
__global__ void k_cast(const float* __restrict__ x, u32* __restrict__ Xh, int total8) {
    int i = blockIdx.x * 256 + threadIdx.x;
    if (i >= total8) return;
    const float4* xv = (const float4*)x;
    float4 a = xv[i * 2], b = xv[i * 2 + 1];
    uint4 o;
    o.x = pk2(a.x, a.y); o.y = pk2(a.z, a.w);
    o.z = pk2(b.x, b.y); o.w = pk2(b.z, b.w);
    ((uint4*)Xh)[i] = o;
}

// ------- aggregation: 4 edge-groups x 16 lanes, U3 row chunks, norm pre-folded -------
__global__ __launch_bounds__(256) void k_agg(
    const u32* __restrict__ Xh,
    const int* __restrict__ st_o, const u64* __restrict__ ev_o,
    const int* __restrict__ st_n, const u64* __restrict__ ev_n,
    const float* __restrict__ dinv,
    u32* __restrict__ fAB, int n)
{
    int wid = (blockIdx.x * 256 + threadIdx.x) >> 6;
    if (wid >= n) return;
    int lane = threadIdx.x & 63;
    int g = lane >> 4, sl = lane & 15;
    const int* st; const u64* ev; const float* dv; int co;
    if (blockIdx.y) { st = st_n; ev = ev_n; dv = dinv + n; co = 48; }
    else            { st = st_o; ev = ev_o; dv = dinv;     co = 0; }

    float a0=0,a1=0,a2=0,a3=0,a4=0,a5=0;
    if (g == 0) {
        float dr = dv[wid];
        float d2 = dr * dr;
        U3 xv = *(const U3*)(Xh + (size_t)wid * 48 + sl * 3);
        a0 = d2 * bl(xv.a); a1 = d2 * bh(xv.a);
        a2 = d2 * bl(xv.b); a3 = d2 * bh(xv.b);
        a4 = d2 * bl(xv.c); a5 = d2 * bh(xv.c);
    }
    int s = st[wid], e = st[wid + 1];
    int j = s + g;
    for (; j + 12 < e; j += 16) {
        u64 e0 = ev[j], e1 = ev[j + 4], e2 = ev[j + 8], e3 = ev[j + 12];
        int u0 = (int)(u32)e0, u1 = (int)(u32)e1, u2 = (int)(u32)e2, u3 = (int)(u32)e3;
        float w0 = __uint_as_float((u32)(e0 >> 32));
        float w1 = __uint_as_float((u32)(e1 >> 32));
        float w2 = __uint_as_float((u32)(e2 >> 32));
        float w3 = __uint_as_float((u32)(e3 >> 32));
        U3 x0 = *(const U3*)(Xh + (size_t)u0 * 48 + sl * 3);
        U3 x1 = *(const U3*)(Xh + (size_t)u1 * 48 + sl * 3);
        U3 x2 = *(const U3*)(Xh + (size_t)u2 * 48 + sl * 3);
        U3 x3 = *(const U3*)(Xh + (size_t)u3 * 48 + sl * 3);
        a0 += w0 * bl(x0.a); a1 += w0 * bh(x0.a);
        a2 += w0 * bl(x0.b); a3 += w0 * bh(x0.b);
        a4 += w0 * bl(x0.c); a5 += w0 * bh(x0.c);
        a0 += w1 * bl(x1.a); a1 += w1 * bh(x1.a);
        a2 += w1 * bl(x1.b); a3 += w1 * bh(x1.b);
        a4 += w1 * bl(x1.c); a5 += w1 * bh(x1.c);
        a0 += w2 * bl(x2.a); a1 += w2 * bh(x2.a);
        a2 += w2 * bl(x2.b); a3 += w2 * bh(x2.b);
        a4 += w2 * bl(x2.c); a5 += w2 * bh(x2.c);
        a0 += w3 * bl(x3.a); a1 += w3 * bh(x3.a);
        a2 += w3 * bl(x3.b); a3 += w3 * bh(x3.b);
        a4 += w3 * bl(x3.c); a5 += w3 * bh(x3.c);
    }
    for (; j < e; j += 4) {
        u64 ee = ev[j];
        int u = (int)(u32)ee;
        float w = __uint_as_float((u32)(ee >> 32));
        U3 xv = *(const U3*)(Xh + (size_t)u * 48 + sl * 3);
        a0 += w * bl(xv.a); a1 += w * bh(xv.a);
        a2 += w * bl(xv.b); a3 += w * bh(xv.b);
        a4 += w * bl(xv.c); a5 += w * bh(xv.c);
    }
    a0 += __shfl_xor(a0, 32); a1 += __shfl_xor(a1, 32); a2 += __shfl_xor(a2, 32);
    a3 += __shfl_xor(a3, 32); a4 += __shfl_xor(a4, 32); a5 += __shfl_xor(a5, 32);
    a0 += __shfl_xor(a0, 16); a1 += __shfl_xor(a1, 16); a2 += __shfl_xor(a2, 16);
    a3 += __shfl_xor(a3, 16); a4 += __shfl_xor(a4, 16); a5 += __shfl_xor(a5, 16);
    if (g == 0) {
        U3 o;
        o.a = pk2(a0, a1); o.b = pk2(a2, a3); o.c = pk2(a4, a5);
        *(U3*)(fAB + (size_t)wid * 96 + co + sl * 3) = o;
    }
}

// ---------------- MFMA GEMM: relu(fAB[N][192]bf16 @ Wt + bias); pool; bf16 H ----------------
__global__ __launch_bounds__(256) void k_mmp(
    const u32* __restrict__ fAB, const unsigned short* __restrict__ Wtg,
    const float* __restrict__ bias, const int* __restrict__ batch,
    const int* __restrict__ gs, const int* __restrict__ ge,
    const float* __restrict__ rinv, float* __restrict__ outp,
    u32* __restrict__ Hh, int writeH, int n)
{
    __shared__ unsigned short sW[96 * 200];       // Wt: [col][k], padded stride 200
    __shared__ float tile[64][100];
    int tid = threadIdx.x;
    for (int m = tid; m < 2304; m += 256) {       // 96*192/8 short8 chunks
        int j = m / 24, k = (m % 24) * 8;
        *(uint4*)&sW[j * 200 + k] = *(const uint4*)&Wtg[j * 192 + k];
    }
    __syncthreads();
    int r0 = blockIdx.x * 64;
    int rows = min(64, n - r0);
    int lane = tid & 63, wv = tid >> 6;
    int rl = lane & 15;
    int kg = lane >> 4;
    int rowg = r0 + wv * 16 + rl;
    int rc = min(rowg, n - 1);
    const short8* Arow = (const short8*)(fAB + (size_t)rc * 96);
    f32x4 acc[6];
    #pragma unroll
    for (int c = 0; c < 6; ++c) acc[c] = (f32x4){0.f, 0.f, 0.f, 0.f};
    #pragma unroll
    for (int t = 0; t < 6; ++t) {
        short8 a = Arow[t * 4 + kg];
        #pragma unroll
        for (int c = 0; c < 6; ++c) {
            short8 b = *(const short8*)&sW[(c * 16 + rl) * 200 + t * 32 + kg * 8];
            acc[c] = __builtin_amdgcn_mfma_f32_16x16x32_bf16(a, b, acc[c], 0, 0, 0);
        }
    }
    #pragma unroll
    for (int c = 0; c < 6; ++c) {
        int col = c * 16 + rl;
        float bs = bias[col];
        #pragma unroll
        for (int q = 0; q < 4; ++q) {
            int lr = wv * 16 + kg * 4 + q;
            tile[lr][col] = fmaxf(acc[c][q] + bs, 0.f);
        }
    }
    __syncthreads();
    if (writeH) {
        for (int m = tid; m < rows * 48; m += 256) {
            int row = m / 48, cp = m % 48;
            Hh[(size_t)(r0 + row) * 48 + cp] = pk2(tile[row][cp * 2], tile[row][cp * 2 + 1]);
        }
    }
    if (tid < DIM) {
        int gfirst = batch[r0], glast = batch[r0 + rows - 1];
        for (int g = gfirst; g <= glast; ++g) {
            int lo = max(gs[g] - r0, 0), hi = min(ge[g] - r0, rows);
            if (lo < hi) {
                float s = 0.f;
                for (int r = lo; r < hi; ++r) s += tile[r][tid];
                atomicAdd(&outp[g * DIM + tid], s * rinv[g]);
            }
        }
    }
}

extern "C" void kernel_launch(void* const* d_in, const int* in_sizes, int n_in,
                              void* d_out, int out_size, void* d_ws, size_t ws_size,
                              hipStream_t stream)
{
    const float* x     = (const float*)d_in[0];
    const int*   ei    = (const int*)d_in[1];
    const float* ew    = (const float*)d_in[2];
    const int*   batch = (const int*)d_in[3];
    const int*   ein   = (const int*)d_in[4];
    const float* ewn   = (const float*)d_in[5];
    const float* W0o = (const float*)d_in[7];
    const float* b0o = (const float*)d_in[8];
    const float* W0n = (const float*)d_in[9];
    const float* b0n = (const float*)d_in[10];
    const float* W0f = (const float*)d_in[11];
    const float* b0f = (const float*)d_in[12];
    const float* W1o = (const float*)d_in[13];
    const float* b1o = (const float*)d_in[14];
    const float* W1n = (const float*)d_in[15];
    const float* b1n = (const float*)d_in[16];
    const float* W1f = (const float*)d_in[17];
    const float* b1f = (const float*)d_in[18];

    const int N = in_sizes[0] / DIM;
    const int E = in_sizes[2];
    float* out = (float*)d_out;

    char* ws = (char*)d_ws;
    size_t off = 0;
    auto alloc = [&](size_t bytes) -> char* {
        char* p = ws + off;
        off += (bytes + 255) & ~(size_t)255;
        return p;
    };
    u64*   zone   = (u64*)alloc((size_t)2 * N * 8 * 8);   // 64B-padded packed counters
    u32*   rank_o = (u32*)alloc((size_t)E * 4);
    u32*   rank_n = (u32*)alloc((size_t)E * 4);
    int*   st_o   = (int*)alloc((size_t)(N + 1) * 4);
    int*   st_n   = (int*)alloc((size_t)(N + 1) * 4);
    u64*   ev_o   = (u64*)alloc((size_t)E * 8);
    u64*   ev_n   = (u64*)alloc((size_t)E * 8);
    float* dinv   = (float*)alloc((size_t)2 * N * 4);
    u32*   Xh     = (u32*)alloc((size_t)N * 48 * 4);
    u32*   Hh     = (u32*)alloc((size_t)N * 48 * 4);
    u32*   fAB    = (u32*)alloc((size_t)N * 96 * 4);
    unsigned short* Wt = (unsigned short*)alloc((size_t)2 * 96 * 192 * 2);
    float* bc     = (float*)alloc(2 * DIM * 4);
    float* rinv   = (float*)alloc(64 * 4);
    int*   gs     = (int*)alloc(64 * 4);
    int*   ge     = (int*)alloc(64 * 4);

    int eb = (E + 255) / 256;

    hipMemsetAsync(zone, 0, (size_t)2 * N * 8 * 8, stream);
    hipMemsetAsync(gs, 0x7f, 64 * 4, stream);
    hipMemsetAsync(ge, 0, 64 * 4, stream);
    hipMemsetAsync(out, 0, (size_t)out_size * 4, stream);

    k_deg<<<dim3(eb, 2), 256, 0, stream>>>(ei, ein, ew, ewn, zone, rank_o, rank_n,
                                           batch, gs, ge, E, N);
    k_dinv<<<(2 * N + 255) / 256, 256, 0, stream>>>(zone, dinv, 2 * N);
    k_scan<<<2, 1024, 0, stream>>>(zone, st_o, st_n, N);
    k_scatter<<<dim3(eb, 2), 256, 0, stream>>>(ei, ew, ein, ewn, rank_o, rank_n,
                                               st_o, st_n, dinv, ev_o, ev_n, E, N);
    k_combine<<<dim3(36, 2), 256, 0, stream>>>(W0o, W0n, W0f, b0o, b0n, b0f,
                                               W1o, W1n, W1f, b1o, b1n, b1f,
                                               Wt, bc, gs, ge, rinv);
    k_cast<<<(N * 12 + 255) / 256, 256, 0, stream>>>(x, Xh, N * 12);

    dim3 ag(((size_t)N * 64 + 255) / 256, 2);
    int mb = (N + 63) / 64;

    // layer 0
    k_agg<<<ag, 256, 0, stream>>>(Xh, st_o, ev_o, st_n, ev_n, dinv, fAB, N);
    k_mmp<<<mb, 256, 0, stream>>>(fAB, Wt, bc, batch, gs, ge, rinv, out, Hh, 1, N);
    // layer 1
    k_agg<<<ag, 256, 0, stream>>>(Hh, st_o, ev_o, st_n, ev_n, dinv, fAB, N);
    k_mmp<<<mb, 256, 0, stream>>>(fAB, Wt + (size_t)96 * 192, bc + DIM, batch, gs, ge, rinv,
                                  out + 64 * DIM, Hh, 0, N);
}

// Round 8
// 302.642 us; speedup vs baseline: 1.4646x; 1.1715x over previous
//
#include <hip/hip_runtime.h>
#include <hip/hip_bf16.h>

#define DIM 96
typedef unsigned int u32;
typedef unsigned long long u64;
typedef __attribute__((ext_vector_type(8))) short short8;
typedef __attribute__((ext_vector_type(4))) float f32x4;

__device__ __forceinline__ u32 bfr(float f) {           // f32 -> bf16 bits (RNE)
    u32 b = __float_as_uint(f);
    return (b + 0x7fffu + ((b >> 16) & 1u)) >> 16;
}
__device__ __forceinline__ u32 pk2(float lo, float hi) { return bfr(lo) | (bfr(hi) << 16); }
__device__ __forceinline__ float bl(u32 u) { return __uint_as_float(u << 16); }
__device__ __forceinline__ float bh(u32 u) { return __uint_as_float(u & 0xffff0000u); }

struct __align__(4) U3 { u32 a, b, c; };

// ---------------- packed degree+count (64B-padded) + rank; bounds tail ----------------
// zone[node*8] = (count << 32) | sum(w * 2^24); one u64 atomic per edge.
__global__ void k_deg(const int* __restrict__ ei, const int* __restrict__ ein,
                      const float* __restrict__ ew, const float* __restrict__ ewn,
                      u64* __restrict__ zone, u32* __restrict__ rank_o, u32* __restrict__ rank_n,
                      const int* __restrict__ batch, int* __restrict__ gs, int* __restrict__ ge,
                      int E, int n) {
    int e = blockIdx.x * 256 + threadIdx.x;
    if (blockIdx.y == 0 && e < n) {
        int b = batch[e];
        if (e == 0 || batch[e - 1] != b) atomicMin(&gs[b], e);
        if (e == n - 1 || batch[e + 1] != b) atomicMax(&ge[b], e + 1);
    }
    if (e >= E) return;
    const int*   I = blockIdx.y ? ein : ei;
    const float* W = blockIdx.y ? ewn : ew;
    u64* z = zone + (blockIdx.y ? (size_t)n * 8 : 0);
    u32* rk = blockIdx.y ? rank_n : rank_o;
    int d = I[E + e];
    u32 wfix = (u32)(W[e] * 16777216.0f + 0.5f);
    u64 old = atomicAdd(&z[(size_t)d * 8], ((u64)1 << 32) | (u64)wfix);
    rk[e] = (u32)(old >> 32);
}

// ------- prep: dinv + segment assignment via wave-aggregated cursor (replaces scan) -------
// seg[node] = (end << 32) | start ; contiguous per node, node order irrelevant.
__global__ __launch_bounds__(256) void k_prep(
    const u64* __restrict__ zone, float* __restrict__ dinv,
    u64* __restrict__ seg, u32* __restrict__ cursor, int n)
{
    int set = blockIdx.y;
    int i = blockIdx.x * 256 + threadIdx.x;
    int lane = threadIdx.x & 63;
    u32 cnt = 0;
    u64 p = 0;
    if (i < n) {
        p = zone[((size_t)set * n + i) * 8];
        cnt = (u32)(p >> 32);
        dinv[set * n + i] = rsqrtf((float)(u32)p * 5.9604644775390625e-8f + 1.0f);
    }
    u32 incl = cnt;
    #pragma unroll
    for (int d = 1; d < 64; d <<= 1) {
        u32 t = __shfl_up(incl, d);
        if (lane >= d) incl += t;
    }
    u32 base = 0;
    if (lane == 63 && incl > 0) base = atomicAdd(&cursor[set], incl);
    base = __shfl(base, 63);
    if (i < n) {
        u32 b = base + incl - cnt;
        seg[(size_t)set * n + i] = ((u64)(b + cnt) << 32) | (u64)b;
    }
}

// ------- atomic-free scatter: ev[start(seg[dst])+rank] = [norm_f32 | src] -------
__global__ void k_scatter(const int* __restrict__ ei, const float* __restrict__ ew,
                          const int* __restrict__ ein, const float* __restrict__ ewn,
                          const u32* __restrict__ rank_o, const u32* __restrict__ rank_n,
                          const u64* __restrict__ seg, const float* __restrict__ dinv,
                          u64* __restrict__ ev_o, u64* __restrict__ ev_n, int E, int n) {
    int e = blockIdx.x * 256 + threadIdx.x;
    if (e >= E) return;
    const int*   I = blockIdx.y ? ein : ei;
    const float* W = blockIdx.y ? ewn : ew;
    const u32*   R = blockIdx.y ? rank_n : rank_o;
    const u64*   sg = seg + (blockIdx.y ? n : 0);
    const float* dv = dinv + (blockIdx.y ? n : 0);
    u64* ev = blockIdx.y ? ev_n : ev_o;
    int s = I[e], d = I[E + e];
    float nrm = dv[s] * W[e] * dv[d];
    int slot = (int)(u32)sg[d] + (int)R[e];
    ev[slot] = ((u64)__float_as_uint(nrm) << 32) | (u32)s;
}

// ---------------- combined weights -> bf16 K-major Wt[96][192]; bias f32; rinv ----------------
__global__ void k_combine(
    const float* __restrict__ W0o, const float* __restrict__ W0n, const float* __restrict__ W0f,
    const float* __restrict__ b0o, const float* __restrict__ b0n, const float* __restrict__ b0f,
    const float* __restrict__ W1o, const float* __restrict__ W1n, const float* __restrict__ W1f,
    const float* __restrict__ b1o, const float* __restrict__ b1n, const float* __restrict__ b1f,
    unsigned short* __restrict__ Wt, float* __restrict__ bc,
    const int* __restrict__ gs, const int* __restrict__ ge, float* __restrict__ rinv)
{
    if (blockIdx.y == 0 && blockIdx.x == 0 && threadIdx.x < 64) {
        int c = ge[threadIdx.x] - gs[threadIdx.x];
        if (c < 1) c = 1;
        rinv[threadIdx.x] = 1.0f / (float)c;
    }
    int l = blockIdx.y;
    const float* Wo = l ? W1o : W0o;
    const float* Wn = l ? W1n : W0n;
    const float* Wf = l ? W1f : W0f;
    const float* bo = l ? b1o : b0o;
    const float* bn = l ? b1n : b0n;
    const float* bf = l ? b1f : b0f;
    unsigned short* wt = Wt + (size_t)l * 96 * 192;
    float* bcl = bc + l * DIM;
    int g = blockIdx.x * 256 + threadIdx.x;
    if (g >= DIM * DIM) return;
    int i = g / DIM, j = g % DIM;       // i = k-row, j = out col
    float so = 0.f, sn = 0.f;
    for (int k = 0; k < DIM; ++k) {
        so += Wo[i * DIM + k] * Wf[k * DIM + j];
        sn += Wn[i * DIM + k] * Wf[(DIM + k) * DIM + j];
    }
    wt[j * 192 + i]      = (unsigned short)bfr(so);
    wt[j * 192 + 96 + i] = (unsigned short)bfr(sn);
    if (i == 0) {
        float s = bf[j];
        for (int k = 0; k < DIM; ++k)
            s += bo[k] * Wf[k * DIM + j] + bn[k] * Wf[(DIM + k) * DIM + j];
        bcl[j] = s;
    }
}

// ---------------- cast x (f32) -> packed bf16 ----------------
__global__ void k_cast(const float* __restrict__ x, u32* __restrict__ Xh, int total8) {
    int i = blockIdx.x * 256 + threadIdx.x;
    if (i >= total8) return;
    const float4* xv = (const float4*)x;
    float4 a = xv[i * 2], b = xv[i * 2 + 1];
    uint4 o;
    o.x = pk2(a.x, a.y); o.y = pk2(a.z, a.w);
    o.z = pk2(b.x, b.y); o.w = pk2(b.z, b.w);
    ((uint4*)Xh)[i] = o;
}

// ------- aggregation: 4 edge-groups x 16 lanes, U3 row chunks, norm pre-folded -------
__global__ __launch_bounds__(256) void k_agg(
    const u32* __restrict__ Xh,
    const u64* __restrict__ seg,
    const u64* __restrict__ ev_o, const u64* __restrict__ ev_n,
    const float* __restrict__ dinv,
    u32* __restrict__ fAB, int n)
{
    int wid = (blockIdx.x * 256 + threadIdx.x) >> 6;
    if (wid >= n) return;
    int lane = threadIdx.x & 63;
    int g = lane >> 4, sl = lane & 15;
    const u64* ev; const u64* sg; const float* dv; int co;
    if (blockIdx.y) { sg = seg + n; ev = ev_n; dv = dinv + n; co = 48; }
    else            { sg = seg;     ev = ev_o; dv = dinv;     co = 0; }

    float a0=0,a1=0,a2=0,a3=0,a4=0,a5=0;
    if (g == 0) {
        float dr = dv[wid];
        float d2 = dr * dr;
        U3 xv = *(const U3*)(Xh + (size_t)wid * 48 + sl * 3);
        a0 = d2 * bl(xv.a); a1 = d2 * bh(xv.a);
        a2 = d2 * bl(xv.b); a3 = d2 * bh(xv.b);
        a4 = d2 * bl(xv.c); a5 = d2 * bh(xv.c);
    }
    u64 sv = sg[wid];
    int s = (int)(u32)sv, e = (int)(u32)(sv >> 32);
    int j = s + g;
    for (; j + 12 < e; j += 16) {
        u64 e0 = ev[j], e1 = ev[j + 4], e2 = ev[j + 8], e3 = ev[j + 12];
        int u0 = (int)(u32)e0, u1 = (int)(u32)e1, u2 = (int)(u32)e2, u3 = (int)(u32)e3;
        float w0 = __uint_as_float((u32)(e0 >> 32));
        float w1 = __uint_as_float((u32)(e1 >> 32));
        float w2 = __uint_as_float((u32)(e2 >> 32));
        float w3 = __uint_as_float((u32)(e3 >> 32));
        U3 x0 = *(const U3*)(Xh + (size_t)u0 * 48 + sl * 3);
        U3 x1 = *(const U3*)(Xh + (size_t)u1 * 48 + sl * 3);
        U3 x2 = *(const U3*)(Xh + (size_t)u2 * 48 + sl * 3);
        U3 x3 = *(const U3*)(Xh + (size_t)u3 * 48 + sl * 3);
        a0 += w0 * bl(x0.a); a1 += w0 * bh(x0.a);
        a2 += w0 * bl(x0.b); a3 += w0 * bh(x0.b);
        a4 += w0 * bl(x0.c); a5 += w0 * bh(x0.c);
        a0 += w1 * bl(x1.a); a1 += w1 * bh(x1.a);
        a2 += w1 * bl(x1.b); a3 += w1 * bh(x1.b);
        a4 += w1 * bl(x1.c); a5 += w1 * bh(x1.c);
        a0 += w2 * bl(x2.a); a1 += w2 * bh(x2.a);
        a2 += w2 * bl(x2.b); a3 += w2 * bh(x2.b);
        a4 += w2 * bl(x2.c); a5 += w2 * bh(x2.c);
        a0 += w3 * bl(x3.a); a1 += w3 * bh(x3.a);
        a2 += w3 * bl(x3.b); a3 += w3 * bh(x3.b);
        a4 += w3 * bl(x3.c); a5 += w3 * bh(x3.c);
    }
    for (; j < e; j += 4) {
        u64 ee = ev[j];
        int u = (int)(u32)ee;
        float w = __uint_as_float((u32)(ee >> 32));
        U3 xv = *(const U3*)(Xh + (size_t)u * 48 + sl * 3);
        a0 += w * bl(xv.a); a1 += w * bh(xv.a);
        a2 += w * bl(xv.b); a3 += w * bh(xv.b);
        a4 += w * bl(xv.c); a5 += w * bh(xv.c);
    }
    a0 += __shfl_xor(a0, 32); a1 += __shfl_xor(a1, 32); a2 += __shfl_xor(a2, 32);
    a3 += __shfl_xor(a3, 32); a4 += __shfl_xor(a4, 32); a5 += __shfl_xor(a5, 32);
    a0 += __shfl_xor(a0, 16); a1 += __shfl_xor(a1, 16); a2 += __shfl_xor(a2, 16);
    a3 += __shfl_xor(a3, 16); a4 += __shfl_xor(a4, 16); a5 += __shfl_xor(a5, 16);
    if (g == 0) {
        U3 o;
        o.a = pk2(a0, a1); o.b = pk2(a2, a3); o.c = pk2(a4, a5);
        *(U3*)(fAB + (size_t)wid * 96 + co + sl * 3) = o;
    }
}

// ---------------- MFMA GEMM: relu(fAB[N][192]bf16 @ Wt + bias); pool; bf16 H ----------------
__global__ __launch_bounds__(256) void k_mmp(
    const u32* __restrict__ fAB, const unsigned short* __restrict__ Wtg,
    const float* __restrict__ bias, const int* __restrict__ batch,
    const int* __restrict__ gs, const int* __restrict__ ge,
    const float* __restrict__ rinv, float* __restrict__ outp,
    u32* __restrict__ Hh, int writeH, int n)
{
    __shared__ unsigned short sW[96 * 200];       // Wt: [col][k], padded stride 200
    __shared__ float tile[64][100];
    int tid = threadIdx.x;
    for (int m = tid; m < 2304; m += 256) {       // 96*192/8 short8 chunks
        int j = m / 24, k = (m % 24) * 8;
        *(uint4*)&sW[j * 200 + k] = *(const uint4*)&Wtg[j * 192 + k];
    }
    __syncthreads();
    int r0 = blockIdx.x * 64;
    int rows = min(64, n - r0);
    int lane = tid & 63, wv = tid >> 6;
    int rl = lane & 15;
    int kg = lane >> 4;
    int rowg = r0 + wv * 16 + rl;
    int rc = min(rowg, n - 1);
    const short8* Arow = (const short8*)(fAB + (size_t)rc * 96);
    f32x4 acc[6];
    #pragma unroll
    for (int c = 0; c < 6; ++c) acc[c] = (f32x4){0.f, 0.f, 0.f, 0.f};
    #pragma unroll
    for (int t = 0; t < 6; ++t) {
        short8 a = Arow[t * 4 + kg];
        #pragma unroll
        for (int c = 0; c < 6; ++c) {
            short8 b = *(const short8*)&sW[(c * 16 + rl) * 200 + t * 32 + kg * 8];
            acc[c] = __builtin_amdgcn_mfma_f32_16x16x32_bf16(a, b, acc[c], 0, 0, 0);
        }
    }
    #pragma unroll
    for (int c = 0; c < 6; ++c) {
        int col = c * 16 + rl;
        float bs = bias[col];
        #pragma unroll
        for (int q = 0; q < 4; ++q) {
            int lr = wv * 16 + kg * 4 + q;
            tile[lr][col] = fmaxf(acc[c][q] + bs, 0.f);
        }
    }
    __syncthreads();
    if (writeH) {
        for (int m = tid; m < rows * 48; m += 256) {
            int row = m / 48, cp = m % 48;
            Hh[(size_t)(r0 + row) * 48 + cp] = pk2(tile[row][cp * 2], tile[row][cp * 2 + 1]);
        }
    }
    if (tid < DIM) {
        int gfirst = batch[r0], glast = batch[r0 + rows - 1];
        for (int g = gfirst; g <= glast; ++g) {
            int lo = max(gs[g] - r0, 0), hi = min(ge[g] - r0, rows);
            if (lo < hi) {
                float s = 0.f;
                for (int r = lo; r < hi; ++r) s += tile[r][tid];
                atomicAdd(&outp[g * DIM + tid], s * rinv[g]);
            }
        }
    }
}

extern "C" void kernel_launch(void* const* d_in, const int* in_sizes, int n_in,
                              void* d_out, int out_size, void* d_ws, size_t ws_size,
                              hipStream_t stream)
{
    const float* x     = (const float*)d_in[0];
    const int*   ei    = (const int*)d_in[1];
    const float* ew    = (const float*)d_in[2];
    const int*   batch = (const int*)d_in[3];
    const int*   ein   = (const int*)d_in[4];
    const float* ewn   = (const float*)d_in[5];
    const float* W0o = (const float*)d_in[7];
    const float* b0o = (const float*)d_in[8];
    const float* W0n = (const float*)d_in[9];
    const float* b0n = (const float*)d_in[10];
    const float* W0f = (const float*)d_in[11];
    const float* b0f = (const float*)d_in[12];
    const float* W1o = (const float*)d_in[13];
    const float* b1o = (const float*)d_in[14];
    const float* W1n = (const float*)d_in[15];
    const float* b1n = (const float*)d_in[16];
    const float* W1f = (const float*)d_in[17];
    const float* b1f = (const float*)d_in[18];

    const int N = in_sizes[0] / DIM;
    const int E = in_sizes[2];
    float* out = (float*)d_out;

    char* ws = (char*)d_ws;
    size_t off = 0;
    auto alloc = [&](size_t bytes) -> char* {
        char* p = ws + off;
        off += (bytes + 255) & ~(size_t)255;
        return p;
    };
    u64*   zone   = (u64*)alloc((size_t)2 * N * 8 * 8);   // 64B-padded packed counters
    u32*   rank_o = (u32*)alloc((size_t)E * 4);
    u32*   rank_n = (u32*)alloc((size_t)E * 4);
    u64*   seg    = (u64*)alloc((size_t)2 * N * 8);
    u64*   ev_o   = (u64*)alloc((size_t)E * 8);
    u64*   ev_n   = (u64*)alloc((size_t)E * 8);
    float* dinv   = (float*)alloc((size_t)2 * N * 4);
    u32*   Xh     = (u32*)alloc((size_t)N * 48 * 4);
    u32*   Hh     = (u32*)alloc((size_t)N * 48 * 4);
    u32*   fAB    = (u32*)alloc((size_t)N * 96 * 4);
    unsigned short* Wt = (unsigned short*)alloc((size_t)2 * 96 * 192 * 2);
    float* bc     = (float*)alloc(2 * DIM * 4);
    float* rinv   = (float*)alloc(64 * 4);
    int*   gs     = (int*)alloc(64 * 4);
    int*   ge     = (int*)alloc(64 * 4);
    u32*   cursor = (u32*)alloc(2 * 4);

    int eb = (E + 255) / 256;
    int nb = (N + 255) / 256;

    hipMemsetAsync(zone, 0, (size_t)2 * N * 8 * 8, stream);
    hipMemsetAsync(gs, 0x7f, 64 * 4, stream);
    hipMemsetAsync(ge, 0, 64 * 4, stream);
    hipMemsetAsync(out, 0, (size_t)out_size * 4, stream);
    hipMemsetAsync(cursor, 0, 2 * 4, stream);

    k_deg<<<dim3(eb, 2), 256, 0, stream>>>(ei, ein, ew, ewn, zone, rank_o, rank_n,
                                           batch, gs, ge, E, N);
    k_prep<<<dim3(nb, 2), 256, 0, stream>>>(zone, dinv, seg, cursor, N);
    k_scatter<<<dim3(eb, 2), 256, 0, stream>>>(ei, ew, ein, ewn, rank_o, rank_n,
                                               seg, dinv, ev_o, ev_n, E, N);
    k_combine<<<dim3(36, 2), 256, 0, stream>>>(W0o, W0n, W0f, b0o, b0n, b0f,
                                               W1o, W1n, W1f, b1o, b1n, b1f,
                                               Wt, bc, gs, ge, rinv);
    k_cast<<<(N * 12 + 255) / 256, 256, 0, stream>>>(x, Xh, N * 12);

    dim3 ag(((size_t)N * 64 + 255) / 256, 2);
    int mb = (N + 63) / 64;

    // layer 0
    k_agg<<<ag, 256, 0, stream>>>(Xh, seg, ev_o, ev_n, dinv, fAB, N);
    k_mmp<<<mb, 256, 0, stream>>>(fAB, Wt, bc, batch, gs, ge, rinv, out, Hh, 1, N);
    // layer 1
    k_agg<<<ag, 256, 0, stream>>>(Hh, seg, ev_o, ev_n, dinv, fAB, N);
    k_mmp<<<mb, 256, 0, stream>>>(fAB, Wt + (size_t)96 * 192, bc + DIM, batch, gs, ge, rinv,
                                  out + 64 * DIM, Hh, 0, N);
}

// Round 9
// 235.728 us; speedup vs baseline: 1.8804x; 1.2839x over previous
//
#include <hip/hip_runtime.h>
#include <hip/hip_bf16.h>

#define DIM 96
#define EBLK 256          // partition blocks per edge set
typedef unsigned int u32;
typedef unsigned long long u64;
typedef __attribute__((ext_vector_type(8))) short short8;
typedef __attribute__((ext_vector_type(4))) float f32x4;

__device__ __forceinline__ u32 bfr(float f) {           // f32 -> bf16 bits (RNE)
    u32 b = __float_as_uint(f);
    return (b + 0x7fffu + ((b >> 16) & 1u)) >> 16;
}
__device__ __forceinline__ u32 pk2(float lo, float hi) { return bfr(lo) | (bfr(hi) << 16); }
__device__ __forceinline__ float bl(u32 u) { return __uint_as_float(u << 16); }
__device__ __forceinline__ float bh(u32 u) { return __uint_as_float(u & 0xffff0000u); }

struct __align__(4) U3 { u32 a, b, c; };

// ---- pass A: per-block LDS histogram over buckets (dst>>7); bounds fused (set 0) ----
__global__ __launch_bounds__(256) void k_hist(
    const int* __restrict__ ei, const int* __restrict__ ein,
    const int* __restrict__ batch, int* __restrict__ gs, int* __restrict__ ge,
    u32* __restrict__ cntmat, int E, int n, int NB, int epb)
{
    int set = blockIdx.y, tid = threadIdx.x;
    if (set == 0) {
        int i = blockIdx.x * 256 + tid;
        if (i < n) {
            int b = batch[i];
            if (i == 0 || batch[i - 1] != b) atomicMin(&gs[b], i);
            if (i == n - 1 || batch[i + 1] != b) atomicMax(&ge[b], i + 1);
        }
    }
    __shared__ u32 hist[512];
    for (int t = tid; t < NB; t += 256) hist[t] = 0;
    __syncthreads();
    const int* D = (set ? ein : ei) + E;
    int lo = blockIdx.x * epb, hi = min(E, lo + epb);
    for (int e = lo + tid; e < hi; e += 256)
        atomicAdd(&hist[((u32)D[e]) >> 7], 1u);
    __syncthreads();
    u32* cm = cntmat + (size_t)set * NB * EBLK;
    for (int t = tid; t < NB; t += 256)
        cm[(size_t)t * EBLK + blockIdx.x] = hist[t];
}

// ---- pass B: per-bucket scan of 256 block counts; bucket base via cursor ----
__global__ __launch_bounds__(256) void k_bscan(
    const u32* __restrict__ cntmat, u32* __restrict__ ebase,
    u64* __restrict__ binfo, u32* __restrict__ cursor, int NB)
{
    int set = blockIdx.y, b = blockIdx.x, tid = threadIdx.x;
    int lane = tid & 63, wv = tid >> 6;
    const u32* cm = cntmat + ((size_t)set * NB + b) * EBLK;
    u32 v = cm[tid];
    u32 incl = v;
    #pragma unroll
    for (int d = 1; d < 64; d <<= 1) {
        u32 t = __shfl_up(incl, d);
        if (lane >= d) incl += t;
    }
    __shared__ u32 wt[4], woff[4], base_s;
    if (lane == 63) wt[wv] = incl;
    __syncthreads();
    if (tid == 0) {
        u32 run = 0;
        #pragma unroll
        for (int k = 0; k < 4; ++k) { woff[k] = run; run += wt[k]; }
        base_s = atomicAdd(&cursor[set], run);
        binfo[(size_t)set * NB + b] = ((u64)run << 32) | (u64)base_s;
    }
    __syncthreads();
    ebase[((size_t)set * NB + b) * EBLK + tid] = base_s + woff[wv] + incl - v;
}

// ---- pass C: partition edges into buckets: evb = [w32 | dl:7 | src:17] ----
__global__ __launch_bounds__(256) void k_part(
    const int* __restrict__ ei, const float* __restrict__ ew,
    const int* __restrict__ ein, const float* __restrict__ ewn,
    const u32* __restrict__ ebase, u64* __restrict__ evb,
    int E, int NB, int epb)
{
    int set = blockIdx.y, tid = threadIdx.x;
    const int*   I = set ? ein : ei;
    const float* W = set ? ewn : ew;
    __shared__ u32 hb[512];
    const u32* eb = ebase + (size_t)set * NB * EBLK;
    for (int t = tid; t < NB; t += 256) hb[t] = eb[(size_t)t * EBLK + blockIdx.x];
    __syncthreads();
    u64* out = evb + (size_t)set * E;
    int lo = blockIdx.x * epb, hi = min(E, lo + epb);
    for (int e = lo + tid; e < hi; e += 256) {
        int s = I[e], d = I[E + e];
        u32 wbits = __float_as_uint(W[e]);
        u32 pos = atomicAdd(&hb[(u32)d >> 7], 1u);
        out[pos] = ((u64)wbits << 32) | ((u32)(d & 127) << 17) | (u32)s;
    }
}

// ---- pass D: per-bucket node counts + weight sums (LDS) -> seg, dinv ----
__global__ __launch_bounds__(256) void k_nprep(
    const u64* __restrict__ evb, const u64* __restrict__ binfo,
    u64* __restrict__ seg, float* __restrict__ dinv, int E, int n, int NB)
{
    int set = blockIdx.y, b = blockIdx.x, tid = threadIdx.x;
    __shared__ u64 acc[128];
    if (tid < 128) acc[tid] = 0;
    __syncthreads();
    u64 bi = binfo[(size_t)set * NB + b];
    u32 base = (u32)bi, tot = (u32)(bi >> 32);
    const u64* ev = evb + (size_t)set * E;
    for (u32 j = tid; j < tot; j += 256) {
        u64 p = ev[base + j];
        u32 dl = ((u32)p >> 17) & 127;
        float w = __uint_as_float((u32)(p >> 32));
        u32 wfix = (u32)(w * 16777216.0f + 0.5f);
        atomicAdd(&acc[dl], ((u64)1 << 32) | (u64)wfix);
    }
    __syncthreads();
    __shared__ u32 wtot;
    u32 cnt = 0, excl = 0;
    if (tid < 128) {
        u64 a = acc[tid];
        cnt = (u32)(a >> 32);
        u32 incl = cnt;
        #pragma unroll
        for (int d = 1; d < 64; d <<= 1) {
            u32 t = __shfl_up(incl, d);
            if ((tid & 63) >= d) incl += t;
        }
        if (tid == 63) wtot = incl;
        excl = incl - cnt;
    }
    __syncthreads();
    if (tid >= 64 && tid < 128) excl += wtot;
    int gnode = b * 128 + tid;
    if (tid < 128 && gnode < n) {
        u32 st = base + excl;
        seg[(size_t)set * n + gnode] = ((u64)(st + cnt) << 32) | (u64)st;
        u64 a = acc[tid];
        dinv[(size_t)set * n + gnode] =
            rsqrtf((float)(u32)a * 5.9604644775390625e-8f + 1.0f);
    }
}

// ---- pass E: bucket -> node-exact CSR with norm folded: ev = [norm_f32 | src] ----
__global__ __launch_bounds__(256) void k_scat2(
    const u64* __restrict__ evb, const u64* __restrict__ binfo,
    const u64* __restrict__ seg, const float* __restrict__ dinv,
    u64* __restrict__ evout, int E, int n, int NB)
{
    int set = blockIdx.y, b = blockIdx.x, tid = threadIdx.x;
    __shared__ u32 rk[128];
    __shared__ u32 st_l[128];
    __shared__ float dv_l[128];
    const float* dv = dinv + (size_t)set * n;
    if (tid < 128) {
        rk[tid] = 0;
        int gnode = b * 128 + tid;
        if (gnode < n) {
            st_l[tid] = (u32)seg[(size_t)set * n + gnode];
            dv_l[tid] = dv[gnode];
        }
    }
    __syncthreads();
    u64 bi = binfo[(size_t)set * NB + b];
    u32 base = (u32)bi, tot = (u32)(bi >> 32);
    const u64* evi = evb + (size_t)set * E;
    u64* out = evout + (size_t)set * E;
    for (u32 j = tid; j < tot; j += 256) {
        u64 p = evi[base + j];
        u32 src = (u32)p & 0x1ffffu;
        u32 dl = ((u32)p >> 17) & 127;
        float w = __uint_as_float((u32)(p >> 32));
        float nrm = dv_l[dl] * w * dv[src];
        u32 slot = st_l[dl] + atomicAdd(&rk[dl], 1u);
        out[slot] = ((u64)__float_as_uint(nrm) << 32) | (u64)src;
    }
}

// ---------------- combined weights -> bf16 K-major Wt[96][192]; bias f32; rinv ----------------
__global__ void k_combine(
    const float* __restrict__ W0o, const float* __restrict__ W0n, const float* __restrict__ W0f,
    const float* __restrict__ b0o, const float* __restrict__ b0n, const float* __restrict__ b0f,
    const float* __restrict__ W1o, const float* __restrict__ W1n, const float* __restrict__ W1f,
    const float* __restrict__ b1o, const float* __restrict__ b1n, const float* __restrict__ b1f,
    unsigned short* __restrict__ Wt, float* __restrict__ bc,
    const int* __restrict__ gs, const int* __restrict__ ge, float* __restrict__ rinv)
{
    if (blockIdx.y == 0 && blockIdx.x == 0 && threadIdx.x < 64) {
        int c = ge[threadIdx.x] - gs[threadIdx.x];
        if (c < 1) c = 1;
        rinv[threadIdx.x] = 1.0f / (float)c;
    }
    int l = blockIdx.y;
    const float* Wo = l ? W1o : W0o;
    const float* Wn = l ? W1n : W0n;
    const float* Wf = l ? W1f : W0f;
    const float* bo = l ? b1o : b0o;
    const float* bn = l ? b1n : b0n;
    const float* bf = l ? b1f : b0f;
    unsigned short* wt = Wt + (size_t)l * 96 * 192;
    float* bcl = bc + l * DIM;
    int g = blockIdx.x * 256 + threadIdx.x;
    if (g >= DIM * DIM) return;
    int i = g / DIM, j = g % DIM;
    float so = 0.f, sn = 0.f;
    for (int k = 0; k < DIM; ++k) {
        so += Wo[i * DIM + k] * Wf[k * DIM + j];
        sn += Wn[i * DIM + k] * Wf[(DIM + k) * DIM + j];
    }
    wt[j * 192 + i]      = (unsigned short)bfr(so);
    wt[j * 192 + 96 + i] = (unsigned short)bfr(sn);
    if (i == 0) {
        float s = bf[j];
        for (int k = 0; k < DIM; ++k)
            s += bo[k] * Wf[k * DIM + j] + bn[k] * Wf[(DIM + k) * DIM + j];
        bcl[j] = s;
    }
}

// ---------------- cast x (f32) -> packed bf16 ----------------
__global__ void k_cast(const float* __restrict__ x, u32* __restrict__ Xh, int total8) {
    int i = blockIdx.x * 256 + threadIdx.x;
    if (i >= total8) return;
    const float4* xv = (const float4*)x;
    float4 a = xv[i * 2], b = xv[i * 2 + 1];
    uint4 o;
    o.x = pk2(a.x, a.y); o.y = pk2(a.z, a.w);
    o.z = pk2(b.x, b.y); o.w = pk2(b.z, b.w);
    ((uint4*)Xh)[i] = o;
}

// ------- aggregation: 4 edge-groups x 16 lanes, U3 row chunks, norm pre-folded -------
__global__ __launch_bounds__(256) void k_agg(
    const u32* __restrict__ Xh,
    const u64* __restrict__ seg,
    const u64* __restrict__ ev_o, const u64* __restrict__ ev_n,
    const float* __restrict__ dinv,
    u32* __restrict__ fAB, int n)
{
    int wid = (blockIdx.x * 256 + threadIdx.x) >> 6;
    if (wid >= n) return;
    int lane = threadIdx.x & 63;
    int g = lane >> 4, sl = lane & 15;
    const u64* ev; const u64* sg; const float* dv; int co;
    if (blockIdx.y) { sg = seg + n; ev = ev_n; dv = dinv + n; co = 48; }
    else            { sg = seg;     ev = ev_o; dv = dinv;     co = 0; }

    float a0=0,a1=0,a2=0,a3=0,a4=0,a5=0;
    if (g == 0) {
        float dr = dv[wid];
        float d2 = dr * dr;
        U3 xv = *(const U3*)(Xh + (size_t)wid * 48 + sl * 3);
        a0 = d2 * bl(xv.a); a1 = d2 * bh(xv.a);
        a2 = d2 * bl(xv.b); a3 = d2 * bh(xv.b);
        a4 = d2 * bl(xv.c); a5 = d2 * bh(xv.c);
    }
    u64 sv = sg[wid];
    int s = (int)(u32)sv, e = (int)(u32)(sv >> 32);
    int j = s + g;
    for (; j + 12 < e; j += 16) {
        u64 e0 = ev[j], e1 = ev[j + 4], e2 = ev[j + 8], e3 = ev[j + 12];
        int u0 = (int)(u32)e0, u1 = (int)(u32)e1, u2 = (int)(u32)e2, u3 = (int)(u32)e3;
        float w0 = __uint_as_float((u32)(e0 >> 32));
        float w1 = __uint_as_float((u32)(e1 >> 32));
        float w2 = __uint_as_float((u32)(e2 >> 32));
        float w3 = __uint_as_float((u32)(e3 >> 32));
        U3 x0 = *(const U3*)(Xh + (size_t)u0 * 48 + sl * 3);
        U3 x1 = *(const U3*)(Xh + (size_t)u1 * 48 + sl * 3);
        U3 x2 = *(const U3*)(Xh + (size_t)u2 * 48 + sl * 3);
        U3 x3 = *(const U3*)(Xh + (size_t)u3 * 48 + sl * 3);
        a0 += w0 * bl(x0.a); a1 += w0 * bh(x0.a);
        a2 += w0 * bl(x0.b); a3 += w0 * bh(x0.b);
        a4 += w0 * bl(x0.c); a5 += w0 * bh(x0.c);
        a0 += w1 * bl(x1.a); a1 += w1 * bh(x1.a);
        a2 += w1 * bl(x1.b); a3 += w1 * bh(x1.b);
        a4 += w1 * bl(x1.c); a5 += w1 * bh(x1.c);
        a0 += w2 * bl(x2.a); a1 += w2 * bh(x2.a);
        a2 += w2 * bl(x2.b); a3 += w2 * bh(x2.b);
        a4 += w2 * bl(x2.c); a5 += w2 * bh(x2.c);
        a0 += w3 * bl(x3.a); a1 += w3 * bh(x3.a);
        a2 += w3 * bl(x3.b); a3 += w3 * bh(x3.b);
        a4 += w3 * bl(x3.c); a5 += w3 * bh(x3.c);
    }
    for (; j < e; j += 4) {
        u64 ee = ev[j];
        int u = (int)(u32)ee;
        float w = __uint_as_float((u32)(ee >> 32));
        U3 xv = *(const U3*)(Xh + (size_t)u * 48 + sl * 3);
        a0 += w * bl(xv.a); a1 += w * bh(xv.a);
        a2 += w * bl(xv.b); a3 += w * bh(xv.b);
        a4 += w * bl(xv.c); a5 += w * bh(xv.c);
    }
    a0 += __shfl_xor(a0, 32); a1 += __shfl_xor(a1, 32); a2 += __shfl_xor(a2, 32);
    a3 += __shfl_xor(a3, 32); a4 += __shfl_xor(a4, 32); a5 += __shfl_xor(a5, 32);
    a0 += __shfl_xor(a0, 16); a1 += __shfl_xor(a1, 16); a2 += __shfl_xor(a2, 16);
    a3 += __shfl_xor(a3, 16); a4 += __shfl_xor(a4, 16); a5 += __shfl_xor(a5, 16);
    if (g == 0) {
        U3 o;
        o.a = pk2(a0, a1); o.b = pk2(a2, a3); o.c = pk2(a4, a5);
        *(U3*)(fAB + (size_t)wid * 96 + co + sl * 3) = o;
    }
}

// ---------------- MFMA GEMM: relu(fAB[N][192]bf16 @ Wt + bias); pool; bf16 H ----------------
__global__ __launch_bounds__(256) void k_mmp(
    const u32* __restrict__ fAB, const unsigned short* __restrict__ Wtg,
    const float* __restrict__ bias, const int* __restrict__ batch,
    const int* __restrict__ gs, const int* __restrict__ ge,
    const float* __restrict__ rinv, float* __restrict__ outp,
    u32* __restrict__ Hh, int writeH, int n)
{
    __shared__ unsigned short sW[96 * 200];
    __shared__ float tile[64][100];
    int tid = threadIdx.x;
    for (int m = tid; m < 2304; m += 256) {
        int j = m / 24, k = (m % 24) * 8;
        *(uint4*)&sW[j * 200 + k] = *(const uint4*)&Wtg[j * 192 + k];
    }
    __syncthreads();
    int r0 = blockIdx.x * 64;
    int rows = min(64, n - r0);
    int lane = tid & 63, wv = tid >> 6;
    int rl = lane & 15;
    int kg = lane >> 4;
    int rowg = r0 + wv * 16 + rl;
    int rc = min(rowg, n - 1);
    const short8* Arow = (const short8*)(fAB + (size_t)rc * 96);
    f32x4 acc[6];
    #pragma unroll
    for (int c = 0; c < 6; ++c) acc[c] = (f32x4){0.f, 0.f, 0.f, 0.f};
    #pragma unroll
    for (int t = 0; t < 6; ++t) {
        short8 a = Arow[t * 4 + kg];
        #pragma unroll
        for (int c = 0; c < 6; ++c) {
            short8 b = *(const short8*)&sW[(c * 16 + rl) * 200 + t * 32 + kg * 8];
            acc[c] = __builtin_amdgcn_mfma_f32_16x16x32_bf16(a, b, acc[c], 0, 0, 0);
        }
    }
    #pragma unroll
    for (int c = 0; c < 6; ++c) {
        int col = c * 16 + rl;
        float bs = bias[col];
        #pragma unroll
        for (int q = 0; q < 4; ++q) {
            int lr = wv * 16 + kg * 4 + q;
            tile[lr][col] = fmaxf(acc[c][q] + bs, 0.f);
        }
    }
    __syncthreads();
    if (writeH) {
        for (int m = tid; m < rows * 48; m += 256) {
            int row = m / 48, cp = m % 48;
            Hh[(size_t)(r0 + row) * 48 + cp] = pk2(tile[row][cp * 2], tile[row][cp * 2 + 1]);
        }
    }
    if (tid < DIM) {
        int gfirst = batch[r0], glast = batch[r0 + rows - 1];
        for (int g = gfirst; g <= glast; ++g) {
            int lo = max(gs[g] - r0, 0), hi = min(ge[g] - r0, rows);
            if (lo < hi) {
                float s = 0.f;
                for (int r = lo; r < hi; ++r) s += tile[r][tid];
                atomicAdd(&outp[g * DIM + tid], s * rinv[g]);
            }
        }
    }
}

extern "C" void kernel_launch(void* const* d_in, const int* in_sizes, int n_in,
                              void* d_out, int out_size, void* d_ws, size_t ws_size,
                              hipStream_t stream)
{
    const float* x     = (const float*)d_in[0];
    const int*   ei    = (const int*)d_in[1];
    const float* ew    = (const float*)d_in[2];
    const int*   batch = (const int*)d_in[3];
    const int*   ein   = (const int*)d_in[4];
    const float* ewn   = (const float*)d_in[5];
    const float* W0o = (const float*)d_in[7];
    const float* b0o = (const float*)d_in[8];
    const float* W0n = (const float*)d_in[9];
    const float* b0n = (const float*)d_in[10];
    const float* W0f = (const float*)d_in[11];
    const float* b0f = (const float*)d_in[12];
    const float* W1o = (const float*)d_in[13];
    const float* b1o = (const float*)d_in[14];
    const float* W1n = (const float*)d_in[15];
    const float* b1n = (const float*)d_in[16];
    const float* W1f = (const float*)d_in[17];
    const float* b1f = (const float*)d_in[18];

    const int N = in_sizes[0] / DIM;
    const int E = in_sizes[2];
    float* out = (float*)d_out;
    const int NB = (N + 127) >> 7;
    const int epb = (E + EBLK - 1) / EBLK;

    char* ws = (char*)d_ws;
    size_t off = 0;
    auto alloc = [&](size_t bytes) -> char* {
        char* p = ws + off;
        off += (bytes + 255) & ~(size_t)255;
        return p;
    };
    u32*   cntmat = (u32*)alloc((size_t)2 * NB * EBLK * 4);
    u32*   ebase  = (u32*)alloc((size_t)2 * NB * EBLK * 4);
    u64*   binfo  = (u64*)alloc((size_t)2 * NB * 8);
    u64*   evb    = (u64*)alloc((size_t)2 * E * 8);
    u64*   ev     = (u64*)alloc((size_t)2 * E * 8);
    u64*   seg    = (u64*)alloc((size_t)2 * N * 8);
    float* dinv   = (float*)alloc((size_t)2 * N * 4);
    u32*   Xh     = (u32*)alloc((size_t)N * 48 * 4);
    u32*   Hh     = (u32*)alloc((size_t)N * 48 * 4);
    u32*   fAB    = (u32*)alloc((size_t)N * 96 * 4);
    unsigned short* Wt = (unsigned short*)alloc((size_t)2 * 96 * 192 * 2);
    float* bc     = (float*)alloc(2 * DIM * 4);
    float* rinv   = (float*)alloc(64 * 4);
    int*   gs     = (int*)alloc(64 * 4);
    int*   ge     = (int*)alloc(64 * 4);
    u32*   cursor = (u32*)alloc(2 * 4);

    hipMemsetAsync(gs, 0x7f, 64 * 4, stream);
    hipMemsetAsync(ge, 0, 64 * 4, stream);
    hipMemsetAsync(out, 0, (size_t)out_size * 4, stream);
    hipMemsetAsync(cursor, 0, 2 * 4, stream);

    k_hist<<<dim3(EBLK, 2), 256, 0, stream>>>(ei, ein, batch, gs, ge, cntmat, E, N, NB, epb);
    k_bscan<<<dim3(NB, 2), 256, 0, stream>>>(cntmat, ebase, binfo, cursor, NB);
    k_part<<<dim3(EBLK, 2), 256, 0, stream>>>(ei, ew, ein, ewn, ebase, evb, E, NB, epb);
    k_nprep<<<dim3(NB, 2), 256, 0, stream>>>(evb, binfo, seg, dinv, E, N, NB);
    k_scat2<<<dim3(NB, 2), 256, 0, stream>>>(evb, binfo, seg, dinv, ev, E, N, NB);
    k_combine<<<dim3(36, 2), 256, 0, stream>>>(W0o, W0n, W0f, b0o, b0n, b0f,
                                               W1o, W1n, W1f, b1o, b1n, b1f,
                                               Wt, bc, gs, ge, rinv);
    k_cast<<<(N * 12 + 255) / 256, 256, 0, stream>>>(x, Xh, N * 12);

    dim3 ag(((size_t)N * 64 + 255) / 256, 2);
    int mb = (N + 63) / 64;

    // layer 0
    k_agg<<<ag, 256, 0, stream>>>(Xh, seg, ev, ev + E, dinv, fAB, N);
    k_mmp<<<mb, 256, 0, stream>>>(fAB, Wt, bc, batch, gs, ge, rinv, out, Hh, 1, N);
    // layer 1
    k_agg<<<ag, 256, 0, stream>>>(Hh, seg, ev, ev + E, dinv, fAB, N);
    k_mmp<<<mb, 256, 0, stream>>>(fAB, Wt + (size_t)96 * 192, bc + DIM, batch, gs, ge, rinv,
                                  out + 64 * DIM, Hh, 0, N);
}